// Round 9
// baseline (31782.208 us; speedup 1.0000x reference)
//
#include <hip/hip_runtime.h>
#include <math.h>

#define NB 256   // batch
#define NT 512   // time steps
#define NF 65    // features
#define NH 512   // hidden
#define NCL 8    // clusters == physical XCDs
#define BPC 32   // blocks per cluster
#define BCL 32   // batch rows per cluster
#define XMS 136  // padded xm row stride (f16)

typedef __attribute__((ext_vector_type(8))) _Float16 f16x8;
typedef __attribute__((ext_vector_type(4))) float   f32x4;
typedef __attribute__((ext_vector_type(4))) unsigned u32x4;

// Tagged dataflow rings: u32 = (step_tag << 16) | f16 value; zero-init == valid
// tag-0 ("t = -1") state. ALL rings depth 4 (r8's depth-2 stats ring was the
// deadlock: fast-block overwrite vs laggard poll of the same parity slot).
__device__ __align__(16) int      g_claim[NCL];
__device__ __align__(16) int      g_lflag[NCL * 64];                 // lay1 poll progress
__device__ __align__(16) unsigned g_h1u[NCL * 4 * BCL * NH];         // [cl][slot][32][512]
__device__ __align__(16) unsigned g_h2u[NCL * 4 * BCL * NH];
__device__ __align__(16) unsigned g_statu[NCL * 4 * BCL * BPC * 2];  // [cl][slot][row][blk][2]
__device__ __align__(16) float    g_pool[NB * NH];
__device__ __align__(16) float    g_Wt[NH * (NH / 2)];
__device__ __align__(16) _Float16 g_xm[(size_t)NB * NT * XMS + 256];

__device__ __forceinline__ float sigm(float v)  { return 1.f / (1.f + __expf(-v)); }
__device__ __forceinline__ float tanh_(float v) { return 1.f - 2.f / (1.f + __expf(2.f * v)); }

// PROVEN (r4-r7) coherence primitives: compiler-generated agent-scope relaxed
// atomic load/store. No inline-asm memory ops anywhere in the main loop — the
// compiler tracks every load, so register spills remain correct.
__device__ __forceinline__ unsigned ld_c(const unsigned* p) {
  return __hip_atomic_load((unsigned*)p, __ATOMIC_RELAXED, __HIP_MEMORY_SCOPE_AGENT);
}
__device__ __forceinline__ void st_c(unsigned* p, unsigned v) {
  __hip_atomic_store(p, v, __ATOMIC_RELAXED, __HIP_MEMORY_SCOPE_AGENT);
}
__device__ __forceinline__ int ld_fl(const int* p) {
  return __hip_atomic_load((int*)p, __ATOMIC_RELAXED, __HIP_MEMORY_SCOPE_AGENT);
}
__device__ __forceinline__ void st_fl(int* p, int v) {
  __hip_atomic_store(p, v, __ATOMIC_RELAXED, __HIP_MEMORY_SCOPE_AGENT);
}
__device__ __forceinline__ unsigned packh(float v, unsigned tag) {
  return (unsigned)__builtin_bit_cast(unsigned short, (_Float16)v) | (tag << 16);
}
__device__ __forceinline__ float f16lo(unsigned u) {
  return (float)__builtin_bit_cast(_Float16, (unsigned short)(u & 0xffffu));
}

#define MF(a,b,c) __builtin_amdgcn_mfma_f32_16x16x32_f16(a,b,c,0,0,0)
#define BF(W,g,c) (*(const f16x8*)((W) + (((g)*16+(c))*64 + l)*8))
#define BI0(g,c)  (*(const f16x8*)(wIH0 + (((g)*5+(c))*64 + l)*8))

__global__ void init_kernel(const float* __restrict__ Wp,
                            const float* __restrict__ x, const int* __restrict__ mask) {
  long i0 = (long)blockIdx.x * blockDim.x + threadIdx.x;
  long n  = (long)gridDim.x * blockDim.x;
  for (long i = i0; i < NCL; i += n) g_claim[i] = 0;
  for (long i = i0; i < NCL*64; i += n) g_lflag[i] = 0;
  for (long i = i0; i < NCL*4*BCL*NH; i += n) { g_h1u[i] = 0u; g_h2u[i] = 0u; }
  for (long i = i0; i < NCL*4*BCL*BPC*2; i += n) g_statu[i] = 0u;
  for (long i = i0; i < NH*(NH/2); i += n) g_Wt[i] = Wp[(i & 255)*NH + (i >> 8)];
  const long total = (long)NB*NT*XMS;
  for (long i = i0; i < total + 256; i += n) {
    if (i >= total) { g_xm[i] = (_Float16)0.f; continue; }
    long row = i / XMS; int col = (int)(i % XMS);
    float v = 0.f;
    if (col < NF)          v = x[row*NF + col];
    else if (col < 2*NF)   v = (float)mask[row*NF + col - NF];
    g_xm[i] = (_Float16)v;
  }
}

// Dataflow GRU, no barriers in the loop. Superstep s:
//   lay0 (w0,w2): poll h1(s-1) tags (+ lay1 flags >= s-1 as ring backpressure),
//     compute h1(s), store tagged (tag s+1, slot s&3).
//   lay1 (w1,w3): poll h1(s-1)[tag s] + h2(s-2)[tag s-1] + stats(s-2)[tag s-1,
//     slot (s+3)&3], post flag s+1, compute h2(s-1) (tag s, slot (s+3)&3),
//     stats(s-1) (tag s, slot s&3), online LN/pooling.
// Overwrite-safety for every ring slot re-verified with 4-deep rotation.
__global__ __launch_bounds__(256, 1) void gru_main(
    const float* __restrict__ Wih0, const float* __restrict__ Whh0,
    const float* __restrict__ bih0, const float* __restrict__ bhh0,
    const float* __restrict__ Wih1, const float* __restrict__ Whh1,
    const float* __restrict__ bih1, const float* __restrict__ bhh1,
    const float* __restrict__ lng,  const float* __restrict__ lnb) {
  extern __shared__ char lds[];
  _Float16* wHH0 = (_Float16*)lds;              // 48KB
  _Float16* wIH1 = (_Float16*)(lds + 49152);    // 48KB
  _Float16* wHH1 = (_Float16*)(lds + 98304);    // 48KB
  _Float16* wIH0 = (_Float16*)(lds + 147456);   // 15KB

  const int tid = threadIdx.x;
  const int w = tid >> 6, l = tid & 63, l15 = l & 15, lgp = l >> 4;
  const int p = w >> 1, lay = w & 1;

  int* bcast = (int*)lds;
  if (tid == 0) {
    unsigned xcc;
    asm volatile("s_getreg_b32 %0, hwreg(HW_REG_XCC_ID)" : "=s"(xcc));
    int c = (int)(xcc & 7u);
    int qq = __hip_atomic_fetch_add(&g_claim[c], 1, __ATOMIC_RELAXED, __HIP_MEMORY_SCOPE_AGENT);
    bcast[0] = c; bcast[1] = qq & 31;
  }
  __syncthreads();
  const int cl = bcast[0], q = bcast[1];
  const int j0 = q * 16;
  __syncthreads();

  for (int e = tid; e < 3*16*NH; e += 256) {
    int k = e & 511, ru = e >> 9;
    int g = ru >> 4, u = ru & 15;
    int src = (g*NH + j0 + u)*NH + k;
    int dst = ((g*16 + (k>>5))*64 + ((((k>>3)&3)<<4) | u))*8 + (k&7);
    wHH0[dst] = (_Float16)Whh0[src];
    wIH1[dst] = (_Float16)Wih1[src];
    wHH1[dst] = (_Float16)Whh1[src];
  }
  for (int e = tid; e < 3*16*160; e += 256) {
    int k = e % 160, ru = e / 160;
    int g = ru >> 4, u = ru & 15;
    float v = (k < 130) ? Wih0[(g*NH + j0 + u)*130 + k] : 0.f;
    int dst = ((g*5 + (k>>5))*64 + ((((k>>3)&3)<<4) | u))*8 + (k&7);
    wIH0[dst] = (_Float16)v;
  }

  const int ucol = j0 + l15;
  const float cbr = lay ? bih1[ucol]+bhh1[ucol]       : bih0[ucol]+bhh0[ucol];
  const float cbz = lay ? bih1[NH+ucol]+bhh1[NH+ucol] : bih0[NH+ucol]+bhh0[NH+ucol];
  const float bin = lay ? bih1[2*NH+ucol]             : bih0[2*NH+ucol];
  const float bhn = lay ? bhh1[2*NH+ucol]             : bhh0[2*NH+ucol];

  const int rdoff = (p*16 + l15)*NH + lgp*8;   // consumer row-slice base (u32)
  const _Float16* xptr = g_xm + ((long)(cl*BCL + p*16 + l15)*NT)*XMS + lgp*8;
  const int* flp = g_lflag + cl*64 + l;

  float hloc[4] = {0,0,0,0};
  float A1[4]={0,0,0,0}, A0[4]={0,0,0,0}, lastc[4]={0,0,0,0};
  f16x8 af1[16], ag2[16];
  unsigned stt[16];
  const f32x4 z4v = {0.f,0.f,0.f,0.f};

  auto lnFinish = [&](bool last) {   // uses hloc BEFORE the gate-math update
    float s  = f16lo(stt[0])+f16lo(stt[2])+f16lo(stt[4])+f16lo(stt[6])
             + f16lo(stt[8])+f16lo(stt[10])+f16lo(stt[12])+f16lo(stt[14]);
    float ss = f16lo(stt[1])+f16lo(stt[3])+f16lo(stt[5])+f16lo(stt[7])
             + f16lo(stt[9])+f16lo(stt[11])+f16lo(stt[13])+f16lo(stt[15]);
    s += __shfl_xor(s,16); ss += __shfl_xor(ss,16);
    s += __shfl_xor(s,32); ss += __shfl_xor(ss,32);
    #pragma unroll
    for (int r = 0; r < 4; r++) {
      float S = __shfl(s, lgp*4+r), SS = __shfl(ss, lgp*4+r);
      float mu = S*(1.f/NH), var = SS*(1.f/NH) - mu*mu;
      float inv = rsqrtf(var + 1e-5f);
      A1[r] += hloc[r]*inv; A0[r] += mu*inv;
      if (last) lastc[r] = (hloc[r]-mu)*inv;
    }
  };

  __syncthreads();   // weight packs visible; last block-wide sync

  for (int s = 0; s <= NT; ++s) {
    if (lay == 0) {
      if (s < NT) {
        f16x8 xmf[5];
        #pragma unroll
        for (int c = 0; c < 5; c++) xmf[c] = *(const f16x8*)(xptr + c*32);
        const unsigned* hb = g_h1u + (size_t)(cl*4 + ((s+3)&3))*BCL*NH + rdoff;
        const unsigned tagH = (unsigned)s;
        unsigned u[128];
        int ok;
        do {
          #pragma unroll
          for (int c = 0; c < 16; c++)
            #pragma unroll
            for (int j = 0; j < 8; j++)
              u[c*8+j] = ld_c(hb + c*32 + j);
          int fl = ld_fl(flp);
          ok = (int)(fl >= s - 1);
          #pragma unroll
          for (int i = 0; i < 128; i++) ok &= (int)((u[i] >> 16) == tagH);
          ok = __all(ok);
          if (!ok) __builtin_amdgcn_s_sleep(1);
        } while (!ok);
        #pragma unroll
        for (int c = 0; c < 16; c++) {
          u32x4 r;
          r[0] = (u[c*8+0]&0xffffu) | (u[c*8+1]<<16);
          r[1] = (u[c*8+2]&0xffffu) | (u[c*8+3]<<16);
          r[2] = (u[c*8+4]&0xffffu) | (u[c*8+5]<<16);
          r[3] = (u[c*8+6]&0xffffu) | (u[c*8+7]<<16);
          af1[c] = __builtin_bit_cast(f16x8, r);
        }
        f32x4 aR=z4v, aZ=z4v, aNi=z4v, aNh=z4v;
        #pragma unroll
        for (int c = 0; c < 16; c++) {
          aR  = MF(af1[c], BF(wHH0,0,c), aR);
          aZ  = MF(af1[c], BF(wHH0,1,c), aZ);
          aNh = MF(af1[c], BF(wHH0,2,c), aNh);
        }
        #pragma unroll
        for (int c = 0; c < 5; c++) {
          aR  = MF(xmf[c], BI0(0,c), aR);
          aZ  = MF(xmf[c], BI0(1,c), aZ);
          aNi = MF(xmf[c], BI0(2,c), aNi);
        }
        unsigned* hw = g_h1u + (size_t)(cl*4 + (s&3))*BCL*NH;
        const unsigned tagW = (unsigned)(s + 1);
        #pragma unroll
        for (int r = 0; r < 4; r++) {
          float rg = sigm(aR[r] + cbr);
          float zg = sigm(aZ[r] + cbz);
          float ng = tanh_(aNi[r] + bin + rg*(aNh[r] + bhn));
          hloc[r] = (1.f-zg)*ng + zg*hloc[r];
          st_c(&hw[(p*16 + lgp*4 + r)*NH + ucol], packh(hloc[r], tagW));
        }
        xptr += XMS;
      }
    } else {   // lay1
      if (s >= 1) {
        const unsigned* hb1 = g_h1u + (size_t)(cl*4 + ((s+3)&3))*BCL*NH + rdoff;
        const unsigned* hb2 = g_h2u + (size_t)(cl*4 + ((s+2)&3))*BCL*NH + rdoff;
        const unsigned* sb  = g_statu + (size_t)(cl*4 + ((s+3)&3))*BCL*BPC*2
                              + ((p*16 + l15)*BPC + lgp*8)*2;
        const unsigned t1 = (unsigned)s, t2 = (unsigned)(s-1);
        unsigned u1[128], u2[128];
        int ok;
        do {
          #pragma unroll
          for (int c = 0; c < 16; c++)
            #pragma unroll
            for (int j = 0; j < 8; j++) {
              u1[c*8+j] = ld_c(hb1 + c*32 + j);
              u2[c*8+j] = ld_c(hb2 + c*32 + j);
            }
          if (s >= 2) {
            #pragma unroll
            for (int i = 0; i < 16; i++) stt[i] = ld_c(sb + i);
          }
          ok = 1;
          #pragma unroll
          for (int i = 0; i < 128; i++) {
            ok &= (int)((u1[i] >> 16) == t1);
            ok &= (int)((u2[i] >> 16) == t2);
          }
          if (s >= 2) {
            #pragma unroll
            for (int i = 0; i < 16; i++) ok &= (int)((stt[i] >> 16) == t2);
          }
          ok = __all(ok);
          if (!ok) __builtin_amdgcn_s_sleep(1);
        } while (!ok);
        if (l == 0) st_fl(g_lflag + cl*64 + q*2 + p, s + 1);
        #pragma unroll
        for (int c = 0; c < 16; c++) {
          u32x4 r1, r2;
          r1[0] = (u1[c*8+0]&0xffffu) | (u1[c*8+1]<<16);
          r1[1] = (u1[c*8+2]&0xffffu) | (u1[c*8+3]<<16);
          r1[2] = (u1[c*8+4]&0xffffu) | (u1[c*8+5]<<16);
          r1[3] = (u1[c*8+6]&0xffffu) | (u1[c*8+7]<<16);
          r2[0] = (u2[c*8+0]&0xffffu) | (u2[c*8+1]<<16);
          r2[1] = (u2[c*8+2]&0xffffu) | (u2[c*8+3]<<16);
          r2[2] = (u2[c*8+4]&0xffffu) | (u2[c*8+5]<<16);
          r2[3] = (u2[c*8+6]&0xffffu) | (u2[c*8+7]<<16);
          af1[c] = __builtin_bit_cast(f16x8, r1);
          ag2[c] = __builtin_bit_cast(f16x8, r2);
        }
        f32x4 aR=z4v, aZ=z4v, aNi=z4v, aNh=z4v;
        #pragma unroll
        for (int c = 0; c < 16; c++) {
          aR  = MF(af1[c], BF(wIH1,0,c), aR);
          aZ  = MF(af1[c], BF(wIH1,1,c), aZ);
          aNi = MF(af1[c], BF(wIH1,2,c), aNi);
          aR  = MF(ag2[c], BF(wHH1,0,c), aR);
          aZ  = MF(ag2[c], BF(wHH1,1,c), aZ);
          aNh = MF(ag2[c], BF(wHH1,2,c), aNh);
        }
        if (s >= 2) lnFinish(false);   // t=s-2, hloc still h2(s-2)
        unsigned* hw = g_h2u + (size_t)(cl*4 + ((s+3)&3))*BCL*NH;
        unsigned* sw = g_statu + (size_t)(cl*4 + (s&3))*BCL*BPC*2;
        const unsigned tagW = (unsigned)s;
        #pragma unroll
        for (int r = 0; r < 4; r++) {
          float rg = sigm(aR[r] + cbr);
          float zg = sigm(aZ[r] + cbz);
          float ng = tanh_(aNi[r] + bin + rg*(aNh[r] + bhn));
          hloc[r] = (1.f-zg)*ng + zg*hloc[r];
          st_c(&hw[(p*16 + lgp*4 + r)*NH + ucol], packh(hloc[r], tagW));
          float v = hloc[r], v2 = hloc[r]*hloc[r];
          v += __shfl_xor(v,1); v2 += __shfl_xor(v2,1);
          v += __shfl_xor(v,2); v2 += __shfl_xor(v2,2);
          v += __shfl_xor(v,4); v2 += __shfl_xor(v2,4);
          v += __shfl_xor(v,8); v2 += __shfl_xor(v2,8);
          if (l15 == 0) {
            unsigned* dp = sw + ((p*16 + lgp*4 + r)*BPC + q)*2;
            st_c(&dp[0], packh(v, tagW));
            st_c(&dp[1], packh(v2, tagW));
          }
        }
      } else {
        if (l == 0) st_fl(g_lflag + cl*64 + q*2 + p, 1);   // s == 0
      }
    }
  }

  if (lay == 1) {   // final LN for t=NT-1: stats tag NT in slot NT&3
    const unsigned* sb = g_statu + (size_t)(cl*4 + (NT&3))*BCL*BPC*2
                         + ((p*16 + l15)*BPC + lgp*8)*2;
    int ok;
    do {
      #pragma unroll
      for (int i = 0; i < 16; i++) stt[i] = ld_c(sb + i);
      ok = 1;
      #pragma unroll
      for (int i = 0; i < 16; i++) ok &= (int)((stt[i] >> 16) == (unsigned)NT);
      ok = __all(ok);
      if (!ok) __builtin_amdgcn_s_sleep(1);
    } while (!ok);
    lnFinish(true);
    float gg = lng[ucol], bb = lnb[ucol];
    #pragma unroll
    for (int r = 0; r < 4; r++) {
      float v = gg*(lastc[r] + (A1[r]-A0[r])*(1.f/NT)) + 2.f*bb;
      g_pool[(cl*BCL + p*16 + lgp*4 + r)*NH + ucol] = v;
    }
  }
}

__global__ __launch_bounds__(256) void proj_kernel(const float* __restrict__ bp,
                                                   float* __restrict__ out) {
  __shared__ float pr[NH];
  int b = blockIdx.x, o = threadIdx.x;
  pr[o] = g_pool[b*NH + o];
  pr[o+256] = g_pool[b*NH + 256 + o];
  __syncthreads();
  float acc = bp[o];
  #pragma unroll 8
  for (int u = 0; u < NH; ++u) acc = fmaf(pr[u], g_Wt[u*256 + o], acc);
  out[b*256 + o] = 0.5f*acc*(1.f + erff(acc*0.70710678118654752f));
}

extern "C" void kernel_launch(void* const* d_in, const int* in_sizes, int n_in,
                              void* d_out, int out_size, void* d_ws, size_t ws_size,
                              hipStream_t stream) {
  const float* x    = (const float*)d_in[0];
  const int*   mask = (const int*)d_in[1];
  const float* Wih0 = (const float*)d_in[2];
  const float* Whh0 = (const float*)d_in[3];
  const float* bih0 = (const float*)d_in[4];
  const float* bhh0 = (const float*)d_in[5];
  const float* Wih1 = (const float*)d_in[6];
  const float* Whh1 = (const float*)d_in[7];
  const float* bih1 = (const float*)d_in[8];
  const float* bhh1 = (const float*)d_in[9];
  const float* lng  = (const float*)d_in[10];
  const float* lnb  = (const float*)d_in[11];
  const float* Wp   = (const float*)d_in[12];
  const float* bp   = (const float*)d_in[13];
  float* out = (float*)d_out;
  (void)in_sizes; (void)n_in; (void)out_size; (void)d_ws; (void)ws_size;

  hipFuncSetAttribute(reinterpret_cast<const void*>(gru_main),
                      hipFuncAttributeMaxDynamicSharedMemorySize, 162816);

  hipLaunchKernelGGL(init_kernel, dim3(2048), dim3(256), 0, stream, Wp, x, mask);
  hipLaunchKernelGGL(gru_main, dim3(256), dim3(256), 162816, stream,
                     Wih0, Whh0, bih0, bhh0, Wih1, Whh1, bih1, bhh1, lng, lnb);
  hipLaunchKernelGGL(proj_kernel, dim3(NB), dim3(256), 0, stream, bp, out);
}

// Round 12
// 12909.573 us; speedup vs baseline: 2.4619x; 2.4619x over previous
//
#include <hip/hip_runtime.h>
#include <math.h>

#define NB 256   // batch
#define NT 512   // time steps
#define NF 65    // features
#define NH 512   // hidden
#define NCL 8    // clusters == physical XCDs
#define BPC 32   // blocks per cluster
#define BCL 32   // batch rows per cluster
#define XMS 136  // padded xm row stride (f16)

typedef __attribute__((ext_vector_type(8))) _Float16 f16x8;
typedef __attribute__((ext_vector_type(4))) float   f32x4;
typedef __attribute__((ext_vector_type(4))) unsigned u32x4;
typedef __attribute__((ext_vector_type(4))) int      i32x4;

// Tagged dataflow rings (r9-proven protocol): u32 = (step_tag<<16) | f16.
// Zero-init == valid tag-0 ("t=-1") state. All rings depth 4.
__device__ __align__(16) int      g_claim[NCL];
__device__ __align__(16) int      g_lflag[NCL * 64];                 // lay1 poll progress
__device__ __align__(16) unsigned g_h1u[NCL * 4 * BCL * NH];         // [cl][slot][32][512]
__device__ __align__(16) unsigned g_h2u[NCL * 4 * BCL * NH];
__device__ __align__(16) unsigned g_statu[NCL * 4 * BCL * BPC * 2];  // [cl][slot][row][blk][2]
__device__ __align__(16) float    g_pool[NB * NH];
__device__ __align__(16) float    g_Wt[NH * (NH / 2)];
__device__ __align__(16) _Float16 g_xm[(size_t)NB * NT * XMS + 256];

__device__ __forceinline__ float sigm(float v)  { return 1.f / (1.f + __expf(-v)); }
__device__ __forceinline__ float tanh_(float v) { return 1.f - 2.f / (1.f + __expf(2.f * v)); }

// COMPILER-MODELED coherent vector load (fixes r10/r11's corruption: hand-asm
// load dests could be spilled to AGPR before the manual vmcnt; an intrinsic
// load is a normal MachineInstr, so the waitcnt pass guards every use, spills
// included). cpol 17 = SC0|SC1 on gfx940+ -> "buffer_load_dwordx4 ... sc0 sc1",
// the r4-r9-proven coherence-point load bits. CK-style intrinsic binding.
__device__ u32x4 llvm_amdgcn_raw_buffer_load_i32x4(i32x4 srsrc, int voffset,
                                                   int soffset, int cpol)
    __asm("llvm.amdgcn.raw.buffer.load.v4i32");
__device__ __forceinline__ u32x4 bld(i32x4 srd, int vo) {
  return llvm_amdgcn_raw_buffer_load_i32x4(srd, vo, 0, 17);
}
__device__ __forceinline__ i32x4 make_srd(const void* base) {
  union { i32x4 v; unsigned u[4]; } s;
  s.u[0] = (unsigned)(unsigned long long)base;
  s.u[1] = (unsigned)(((unsigned long long)base) >> 32);  // stride = 0
  s.u[2] = 0xFFFFFFFFu;                                   // no bounds check
  s.u[3] = 0x00020000u;                                   // raw dword config
  return s.v;
}
// Anti-hoist for readonly intrinsic loads inside poll loops (LICM would spin
// on stale registers forever otherwise).
#define MEMBAR() asm volatile("" ::: "memory");

// PROVEN coherence store side (r4-r9): agent-scope relaxed atomic stores.
__device__ __forceinline__ void st_c(unsigned* p, unsigned v) {
  __hip_atomic_store(p, v, __ATOMIC_RELAXED, __HIP_MEMORY_SCOPE_AGENT);
}
__device__ __forceinline__ int ld_fl(const int* p) {
  return __hip_atomic_load((int*)p, __ATOMIC_RELAXED, __HIP_MEMORY_SCOPE_AGENT);
}
__device__ __forceinline__ void st_fl(int* p, int v) {
  __hip_atomic_store(p, v, __ATOMIC_RELAXED, __HIP_MEMORY_SCOPE_AGENT);
}
__device__ __forceinline__ unsigned packh(float v, unsigned tag) {
  return (unsigned)__builtin_bit_cast(unsigned short, (_Float16)v) | (tag << 16);
}
__device__ __forceinline__ float f16lo(unsigned u) {
  return (float)__builtin_bit_cast(_Float16, (unsigned short)(u & 0xffffu));
}
__device__ __forceinline__ f16x8 unpk(u32x4 a, u32x4 b) {
  u32x4 r;
  r[0] = (a[0] & 0xffffu) | (a[1] << 16);
  r[1] = (a[2] & 0xffffu) | (a[3] << 16);
  r[2] = (b[0] & 0xffffu) | (b[1] << 16);
  r[3] = (b[2] & 0xffffu) | (b[3] << 16);
  return __builtin_bit_cast(f16x8, r);
}

#define CK4(OK,D,T) { OK &= (int)(((D)[0]>>16)==(T)); OK &= (int)(((D)[1]>>16)==(T)); \
                      OK &= (int)(((D)[2]>>16)==(T)); OK &= (int)(((D)[3]>>16)==(T)); }
#define MF(a,b,c) __builtin_amdgcn_mfma_f32_16x16x32_f16(a,b,c,0,0,0)
#define BF(W,g,c) (*(const f16x8*)((W) + (((g)*16+(c))*64 + l)*8))
#define BI0(g,c)  (*(const f16x8*)(wIH0 + (((g)*5+(c))*64 + l)*8))

__global__ void init_kernel(const float* __restrict__ Wp,
                            const float* __restrict__ x, const int* __restrict__ mask) {
  long i0 = (long)blockIdx.x * blockDim.x + threadIdx.x;
  long n  = (long)gridDim.x * blockDim.x;
  for (long i = i0; i < NCL; i += n) g_claim[i] = 0;
  for (long i = i0; i < NCL*64; i += n) g_lflag[i] = 0;
  for (long i = i0; i < NCL*4*BCL*NH; i += n) { g_h1u[i] = 0u; g_h2u[i] = 0u; }
  for (long i = i0; i < NCL*4*BCL*BPC*2; i += n) g_statu[i] = 0u;
  for (long i = i0; i < NH*(NH/2); i += n) g_Wt[i] = Wp[(i & 255)*NH + (i >> 8)];
  const long total = (long)NB*NT*XMS;
  for (long i = i0; i < total + 256; i += n) {
    if (i >= total) { g_xm[i] = (_Float16)0.f; continue; }
    long row = i / XMS; int col = (int)(i % XMS);
    float v = 0.f;
    if (col < NF)          v = x[row*NF + col];
    else if (col < 2*NF)   v = (float)mask[row*NF + col - NF];
    g_xm[i] = (_Float16)v;
  }
}

// Dataflow GRU (r9 protocol verbatim; buffer-intrinsic poll loads; two-phase
// lay1 poll + early MFMAs to shorten the post-arrival critical path).
//   lay0 (w0,w2): ih0 MFMAs early; poll h1(s-1) tags + lay1 flags >= s-1;
//     48 hh0 MFMAs; compute h1(s); store tagged (tag s+1, slot s&3).
//   lay1 (w1,w3): phase1 poll h2(s-2)[tag s-1] + stats[tag s-1] (stale ->
//     first-hit), 48 hh1 MFMAs; phase2 poll h1(s-1)[tag s]; post flag s+1;
//     48 ih1 MFMAs; LN finish; compute h2(s-1) (tag s); stats(s-1) (tag s).
__global__ __launch_bounds__(256, 1) void gru_main(
    const float* __restrict__ Wih0, const float* __restrict__ Whh0,
    const float* __restrict__ bih0, const float* __restrict__ bhh0,
    const float* __restrict__ Wih1, const float* __restrict__ Whh1,
    const float* __restrict__ bih1, const float* __restrict__ bhh1,
    const float* __restrict__ lng,  const float* __restrict__ lnb) {
  extern __shared__ char lds[];
  _Float16* wHH0 = (_Float16*)lds;              // 48KB
  _Float16* wIH1 = (_Float16*)(lds + 49152);    // 48KB
  _Float16* wHH1 = (_Float16*)(lds + 98304);    // 48KB
  _Float16* wIH0 = (_Float16*)(lds + 147456);   // 15KB

  const int tid = threadIdx.x;
  const int w = tid >> 6, l = tid & 63, l15 = l & 15, lgp = l >> 4;
  const int p = w >> 1, lay = w & 1;

  int* bcast = (int*)lds;
  if (tid == 0) {
    unsigned xcc;
    asm volatile("s_getreg_b32 %0, hwreg(HW_REG_XCC_ID)" : "=s"(xcc));
    int c = (int)(xcc & 7u);
    int qq = __hip_atomic_fetch_add(&g_claim[c], 1, __ATOMIC_RELAXED, __HIP_MEMORY_SCOPE_AGENT);
    bcast[0] = c; bcast[1] = qq & 31;
  }
  __syncthreads();
  const int cl = bcast[0], q = bcast[1];
  const int j0 = q * 16;
  __syncthreads();

  for (int e = tid; e < 3*16*NH; e += 256) {
    int k = e & 511, ru = e >> 9;
    int g = ru >> 4, u = ru & 15;
    int src = (g*NH + j0 + u)*NH + k;
    int dst = ((g*16 + (k>>5))*64 + ((((k>>3)&3)<<4) | u))*8 + (k&7);
    wHH0[dst] = (_Float16)Whh0[src];
    wIH1[dst] = (_Float16)Wih1[src];
    wHH1[dst] = (_Float16)Whh1[src];
  }
  for (int e = tid; e < 3*16*160; e += 256) {
    int k = e % 160, ru = e / 160;
    int g = ru >> 4, u = ru & 15;
    float v = (k < 130) ? Wih0[(g*NH + j0 + u)*130 + k] : 0.f;
    int dst = ((g*5 + (k>>5))*64 + ((((k>>3)&3)<<4) | u))*8 + (k&7);
    wIH0[dst] = (_Float16)v;
  }

  const int ucol = j0 + l15;
  const float cbr = lay ? bih1[ucol]+bhh1[ucol]       : bih0[ucol]+bhh0[ucol];
  const float cbz = lay ? bih1[NH+ucol]+bhh1[NH+ucol] : bih0[NH+ucol]+bhh0[NH+ucol];
  const float bin = lay ? bih1[2*NH+ucol]             : bih0[2*NH+ucol];
  const float bhn = lay ? bhh1[2*NH+ucol]             : bhh0[2*NH+ucol];

  const int rdoff = (p*16 + l15)*NH + lgp*8;   // consumer row-slice base (u32)
  const int stoff = ((p*16 + l15)*BPC + lgp*8)*2;
  const _Float16* xptr = g_xm + ((long)(cl*BCL + p*16 + l15)*NT)*XMS + lgp*8;
  const int* flp = g_lflag + cl*64 + l;

  const i32x4 srdH1 = make_srd(g_h1u + (size_t)cl*4*BCL*NH);
  const i32x4 srdH2 = make_srd(g_h2u + (size_t)cl*4*BCL*NH);
  const i32x4 srdST = make_srd(g_statu + (size_t)cl*4*BCL*BPC*2);

  float hloc[4] = {0,0,0,0};
  float A1[4]={0,0,0,0}, A0[4]={0,0,0,0}, lastc[4]={0,0,0,0};
  u32x4 STv[4];
  const f32x4 z4v = {0.f,0.f,0.f,0.f};

  auto lnFinish = [&](bool last) {   // uses hloc BEFORE the gate-math update
    float s  = f16lo(STv[0][0])+f16lo(STv[0][2])+f16lo(STv[1][0])+f16lo(STv[1][2])
             + f16lo(STv[2][0])+f16lo(STv[2][2])+f16lo(STv[3][0])+f16lo(STv[3][2]);
    float ss = f16lo(STv[0][1])+f16lo(STv[0][3])+f16lo(STv[1][1])+f16lo(STv[1][3])
             + f16lo(STv[2][1])+f16lo(STv[2][3])+f16lo(STv[3][1])+f16lo(STv[3][3]);
    s += __shfl_xor(s,16); ss += __shfl_xor(ss,16);
    s += __shfl_xor(s,32); ss += __shfl_xor(ss,32);
    #pragma unroll
    for (int r = 0; r < 4; r++) {
      float S = __shfl(s, lgp*4+r), SS = __shfl(ss, lgp*4+r);
      float mu = S*(1.f/NH), var = SS*(1.f/NH) - mu*mu;
      float inv = rsqrtf(var + 1e-5f);
      A1[r] += hloc[r]*inv; A0[r] += mu*inv;
      if (last) lastc[r] = (hloc[r]-mu)*inv;
    }
  };

  __syncthreads();   // weight packs visible; last block-wide sync

  for (int s = 0; s <= NT; ++s) {
    if (lay == 0) {
      if (s < NT) {
        f16x8 xmf[5];
        #pragma unroll
        for (int c = 0; c < 5; c++) xmf[c] = *(const f16x8*)(xptr + c*32);
        // ih0 MFMAs first (xm is stable -> off the handoff critical path)
        f32x4 aR=z4v, aZ=z4v, aNi=z4v, aNh=z4v;
        #pragma unroll
        for (int c = 0; c < 5; c++) {
          aR  = MF(xmf[c], BI0(0,c), aR);
          aZ  = MF(xmf[c], BI0(1,c), aZ);
          aNi = MF(xmf[c], BI0(2,c), aNi);
        }
        const int vb = 4*(((s+3)&3)*BCL*NH + rdoff);
        const unsigned tagH = (unsigned)s;
        u32x4 U1[32];
        int ok;
        do {
          MEMBAR()
          #pragma unroll
          for (int c = 0; c < 16; c++) {
            U1[2*c]   = bld(srdH1, vb + c*128);
            U1[2*c+1] = bld(srdH1, vb + c*128 + 16);
          }
          int fl = ld_fl(flp);
          ok = (int)(fl >= s - 1);
          #pragma unroll
          for (int i = 0; i < 32; i++) CK4(ok, U1[i], tagH)
          ok = __all(ok);
          if (!ok) __builtin_amdgcn_s_sleep(4);
        } while (!ok);
        #pragma unroll
        for (int c = 0; c < 16; c++) {
          f16x8 a = unpk(U1[2*c], U1[2*c+1]);
          aR  = MF(a, BF(wHH0,0,c), aR);
          aZ  = MF(a, BF(wHH0,1,c), aZ);
          aNh = MF(a, BF(wHH0,2,c), aNh);
        }
        unsigned* hw = g_h1u + (size_t)(cl*4 + (s&3))*BCL*NH;
        const unsigned tagW = (unsigned)(s + 1);
        #pragma unroll
        for (int r = 0; r < 4; r++) {
          float rg = sigm(aR[r] + cbr);
          float zg = sigm(aZ[r] + cbz);
          float ng = tanh_(aNi[r] + bin + rg*(aNh[r] + bhn));
          hloc[r] = (1.f-zg)*ng + zg*hloc[r];
          st_c(&hw[(p*16 + lgp*4 + r)*NH + ucol], packh(hloc[r], tagW));
        }
        xptr += XMS;
      }
    } else {   // lay1
      if (s >= 1) {
        const unsigned t1 = (unsigned)s, t2 = (unsigned)(s-1);
        f16x8 ag2[16];
        f32x4 aR=z4v, aZ=z4v, aNi=z4v, aNh=z4v;
        {  // ---- phase 1: stale-by-construction operands (h2(s-2), stats) ----
          const int vb2 = 4*(((s+2)&3)*BCL*NH + rdoff);
          const int vbs = 4*(((s+3)&3)*BCL*BPC*2 + stoff);
          u32x4 U2[32];
          int ok;
          do {
            MEMBAR()
            #pragma unroll
            for (int c = 0; c < 16; c++) {
              U2[2*c]   = bld(srdH2, vb2 + c*128);
              U2[2*c+1] = bld(srdH2, vb2 + c*128 + 16);
            }
            if (s >= 2) {
              STv[0] = bld(srdST, vbs);      STv[1] = bld(srdST, vbs + 16);
              STv[2] = bld(srdST, vbs + 32); STv[3] = bld(srdST, vbs + 48);
            }
            ok = 1;
            #pragma unroll
            for (int i = 0; i < 32; i++) CK4(ok, U2[i], t2)
            if (s >= 2) {
              #pragma unroll
              for (int i = 0; i < 4; i++) CK4(ok, STv[i], t2)
            }
            ok = __all(ok);
            if (!ok) __builtin_amdgcn_s_sleep(4);
          } while (!ok);
          #pragma unroll
          for (int c = 0; c < 16; c++) ag2[c] = unpk(U2[2*c], U2[2*c+1]);
        }
        #pragma unroll
        for (int c = 0; c < 16; c++) {   // hh1 MFMAs before the fresh-data spin
          aR  = MF(ag2[c], BF(wHH1,0,c), aR);
          aZ  = MF(ag2[c], BF(wHH1,1,c), aZ);
          aNh = MF(ag2[c], BF(wHH1,2,c), aNh);
        }
        {  // ---- phase 2: fresh h1(s-1) ----
          const int vb1 = 4*(((s+3)&3)*BCL*NH + rdoff);
          u32x4 U1[32];
          int ok;
          do {
            MEMBAR()
            #pragma unroll
            for (int c = 0; c < 16; c++) {
              U1[2*c]   = bld(srdH1, vb1 + c*128);
              U1[2*c+1] = bld(srdH1, vb1 + c*128 + 16);
            }
            ok = 1;
            #pragma unroll
            for (int i = 0; i < 32; i++) CK4(ok, U1[i], t1)
            ok = __all(ok);
            if (!ok) __builtin_amdgcn_s_sleep(4);
          } while (!ok);
          if (l == 0) st_fl(g_lflag + cl*64 + q*2 + p, s + 1);
          #pragma unroll
          for (int c = 0; c < 16; c++) {
            f16x8 a = unpk(U1[2*c], U1[2*c+1]);
            aR  = MF(a, BF(wIH1,0,c), aR);
            aZ  = MF(a, BF(wIH1,1,c), aZ);
            aNi = MF(a, BF(wIH1,2,c), aNi);
          }
        }
        if (s >= 2) lnFinish(false);   // t=s-2, hloc still h2(s-2)
        unsigned* hw = g_h2u + (size_t)(cl*4 + ((s+3)&3))*BCL*NH;
        unsigned* sw = g_statu + (size_t)(cl*4 + (s&3))*BCL*BPC*2;
        const unsigned tagW = (unsigned)s;
        #pragma unroll
        for (int r = 0; r < 4; r++) {
          float rg = sigm(aR[r] + cbr);
          float zg = sigm(aZ[r] + cbz);
          float ng = tanh_(aNi[r] + bin + rg*(aNh[r] + bhn));
          hloc[r] = (1.f-zg)*ng + zg*hloc[r];
          st_c(&hw[(p*16 + lgp*4 + r)*NH + ucol], packh(hloc[r], tagW));
          float v = hloc[r], v2 = hloc[r]*hloc[r];
          v += __shfl_xor(v,1); v2 += __shfl_xor(v2,1);
          v += __shfl_xor(v,2); v2 += __shfl_xor(v2,2);
          v += __shfl_xor(v,4); v2 += __shfl_xor(v2,4);
          v += __shfl_xor(v,8); v2 += __shfl_xor(v2,8);
          if (l15 == 0) {
            unsigned* dp = sw + ((p*16 + lgp*4 + r)*BPC + q)*2;
            st_c(&dp[0], packh(v, tagW));
            st_c(&dp[1], packh(v2, tagW));
          }
        }
      } else {
        if (l == 0) st_fl(g_lflag + cl*64 + q*2 + p, 1);   // s == 0
      }
    }
  }

  if (lay == 1) {   // final LN for t=NT-1: stats tag NT in slot NT&3
    const int vbs = 4*((NT&3)*BCL*BPC*2 + stoff);
    int ok;
    do {
      MEMBAR()
      STv[0] = bld(srdST, vbs);      STv[1] = bld(srdST, vbs + 16);
      STv[2] = bld(srdST, vbs + 32); STv[3] = bld(srdST, vbs + 48);
      ok = 1;
      #pragma unroll
      for (int i = 0; i < 4; i++) CK4(ok, STv[i], (unsigned)NT)
      ok = __all(ok);
      if (!ok) __builtin_amdgcn_s_sleep(4);
    } while (!ok);
    lnFinish(true);
    float gg = lng[ucol], bb = lnb[ucol];
    #pragma unroll
    for (int r = 0; r < 4; r++) {
      float v = gg*(lastc[r] + (A1[r]-A0[r])*(1.f/NT)) + 2.f*bb;
      g_pool[(cl*BCL + p*16 + lgp*4 + r)*NH + ucol] = v;
    }
  }
}

__global__ __launch_bounds__(256) void proj_kernel(const float* __restrict__ bp,
                                                   float* __restrict__ out) {
  __shared__ float pr[NH];
  int b = blockIdx.x, o = threadIdx.x;
  pr[o] = g_pool[b*NH + o];
  pr[o+256] = g_pool[b*NH + 256 + o];
  __syncthreads();
  float acc = bp[o];
  #pragma unroll 8
  for (int u = 0; u < NH; ++u) acc = fmaf(pr[u], g_Wt[u*256 + o], acc);
  out[b*256 + o] = 0.5f*acc*(1.f + erff(acc*0.70710678118654752f));
}

extern "C" void kernel_launch(void* const* d_in, const int* in_sizes, int n_in,
                              void* d_out, int out_size, void* d_ws, size_t ws_size,
                              hipStream_t stream) {
  const float* x    = (const float*)d_in[0];
  const int*   mask = (const int*)d_in[1];
  const float* Wih0 = (const float*)d_in[2];
  const float* Whh0 = (const float*)d_in[3];
  const float* bih0 = (const float*)d_in[4];
  const float* bhh0 = (const float*)d_in[5];
  const float* Wih1 = (const float*)d_in[6];
  const float* Whh1 = (const float*)d_in[7];
  const float* bih1 = (const float*)d_in[8];
  const float* bhh1 = (const float*)d_in[9];
  const float* lng  = (const float*)d_in[10];
  const float* lnb  = (const float*)d_in[11];
  const float* Wp   = (const float*)d_in[12];
  const float* bp   = (const float*)d_in[13];
  float* out = (float*)d_out;
  (void)in_sizes; (void)n_in; (void)out_size; (void)d_ws; (void)ws_size;

  hipFuncSetAttribute(reinterpret_cast<const void*>(gru_main),
                      hipFuncAttributeMaxDynamicSharedMemorySize, 162816);

  hipLaunchKernelGGL(init_kernel, dim3(2048), dim3(256), 0, stream, Wp, x, mask);
  hipLaunchKernelGGL(gru_main, dim3(256), dim3(256), 162816, stream,
                     Wih0, Whh0, bih0, bhh0, Wih1, Whh1, bih1, bhh1, lng, lnb);
  hipLaunchKernelGGL(proj_kernel, dim3(NB), dim3(256), 0, stream, bp, out);
}

// Round 14
// 3774.916 us; speedup vs baseline: 8.4193x; 3.4198x over previous
//
#include <hip/hip_runtime.h>
#include <math.h>

#define NB 256   // batch
#define NT 512   // time steps
#define NF 65    // features
#define NH 512   // hidden
#define NCL 8    // clusters == physical XCDs
#define BPC 32   // blocks per cluster
#define BCL 32   // batch rows per cluster
#define XMS 136  // padded xm row stride (f16)
#define STPL (NCL*BCL*BPC*2)   // stats plane (one parity), floats

typedef __attribute__((ext_vector_type(8))) _Float16 f16x8;
typedef __attribute__((ext_vector_type(4))) float   f32x4;
typedef __attribute__((ext_vector_type(4))) unsigned u32x4;
typedef __attribute__((ext_vector_type(4))) int      i32x4;

// r13 schedule + r12-proven spill-safe loads. Rings: h depth-4, stats parity-2.
__device__ __align__(16) int      g_claim[NCL];
__device__ __align__(16) int      g_cnt[NCL];                  // cluster arrive counter
__device__ __align__(16) _Float16 g_h1[NCL*4*BCL*NH];          // [cl][slot][32][512]
__device__ __align__(16) _Float16 g_h2[NCL*4*BCL*NH];
__device__ __align__(16) float    g_stats[2][STPL];            // t-parity
__device__ __align__(16) float    g_pool[NB*NH];
__device__ __align__(16) float    g_Wt[NH*(NH/2)];
__device__ __align__(16) _Float16 g_xm[(size_t)NB*NT*XMS + 256];

__device__ __forceinline__ float sigm(float v)  { return 1.f/(1.f+__expf(-v)); }
__device__ __forceinline__ float tanh_(float v) { return 1.f-2.f/(1.f+__expf(2.f*v)); }

// COMPILER-MODELED coherent load (r12-proven): normal MachineInstr, so the
// waitcnt pass guards every use INCLUDING register spills (r11/r13's NaN was
// hand-asm load dests spilled before the manual vmcnt). cpol 17 = SC0|SC1.
__device__ u32x4 llvm_amdgcn_raw_buffer_load_i32x4(i32x4 srsrc, int voffset,
                                                   int soffset, int cpol)
    __asm("llvm.amdgcn.raw.buffer.load.v4i32");
__device__ __forceinline__ u32x4 bld(i32x4 srd, int vo) {
  return llvm_amdgcn_raw_buffer_load_i32x4(srd, vo, 0, 17);
}
__device__ __forceinline__ f16x8 bldh(i32x4 srd, int vo) {
  return __builtin_bit_cast(f16x8, bld(srd, vo));
}
__device__ __forceinline__ i32x4 make_srd(const void* base) {
  union { i32x4 v; unsigned u[4]; } s;
  s.u[0] = (unsigned)(unsigned long long)base;
  s.u[1] = (unsigned)(((unsigned long long)base) >> 32);  // stride = 0
  s.u[2] = 0xFFFFFFFFu;                                   // no bounds check
  s.u[3] = 0x00020000u;                                   // raw dword config
  return s.v;
}

// PROVEN store side (r4-r13): agent-scope relaxed atomic stores.
__device__ __forceinline__ void st_c(unsigned* p, unsigned v) {
  __hip_atomic_store(p, v, __ATOMIC_RELAXED, __HIP_MEMORY_SCOPE_AGENT);
}
__device__ __forceinline__ void st_c64(unsigned long long* p, unsigned long long v) {
  __hip_atomic_store(p, v, __ATOMIC_RELAXED, __HIP_MEMORY_SCOPE_AGENT);
}
__device__ __forceinline__ int ld_fl(const int* p) {
  return __hip_atomic_load((int*)p, __ATOMIC_RELAXED, __HIP_MEMORY_SCOPE_AGENT);
}

#define MF(a,b,c) __builtin_amdgcn_mfma_f32_16x16x32_f16(a,b,c,0,0,0)
#define BF(W,g,c) (*(const f16x8*)((W) + (((g)*16+(c))*64 + l)*8))
#define BI0(g,c)  (*(const f16x8*)(wIH0 + (((g)*5+(c))*64 + l)*8))

__global__ void init_kernel(const float* __restrict__ Wp,
                            const float* __restrict__ x, const int* __restrict__ mask) {
  long i0 = (long)blockIdx.x * blockDim.x + threadIdx.x;
  long n  = (long)gridDim.x * blockDim.x;
  for (long i = i0; i < NCL; i += n) { g_claim[i] = 0; g_cnt[i] = 0; }
  for (long i = i0; i < NCL*4*BCL*NH; i += n) { g_h1[i]=(_Float16)0.f; g_h2[i]=(_Float16)0.f; }
  for (long i = i0; i < 2*STPL; i += n) ((float*)g_stats)[i] = 0.f;
  for (long i = i0; i < NH*(NH/2); i += n) g_Wt[i] = Wp[(i & 255)*NH + (i >> 8)];
  const long total = (long)NB*NT*XMS;
  for (long i = i0; i < total + 256; i += n) {
    if (i >= total) { g_xm[i] = (_Float16)0.f; continue; }
    long row = i / XMS; int col = (int)(i % XMS);
    float v = 0.f;
    if (col < NF)          v = x[row*NF + col];
    else if (col < 2*NF)   v = (float)mask[row*NF + col - NF];
    g_xm[i] = (_Float16)v;
  }
}

// Skewed layer-specialized superstep GRU (r13 schedule, audited):
// superstep s: lay0 (w0,w2) computes h1(s) [only tight edge: h1(s-1)];
// lay1 (w1,w3) computes h2(s-2) [h1(s-2): prefetched across the barrier;
// h2(s-3), stats(s-3): 1 barrier old, loaded at top]. Tail: drain-syncthreads,
// tid0 counter++, cross-barrier prefetch issue, per-wave counter poll.
__global__ __launch_bounds__(256, 1) void gru_main(
    const float* __restrict__ Wih0, const float* __restrict__ Whh0,
    const float* __restrict__ bih0, const float* __restrict__ bhh0,
    const float* __restrict__ Wih1, const float* __restrict__ Whh1,
    const float* __restrict__ bih1, const float* __restrict__ bhh1,
    const float* __restrict__ lng,  const float* __restrict__ lnb) {
  extern __shared__ char lds[];
  _Float16* wHH0 = (_Float16*)lds;              // 48KB
  _Float16* wIH1 = (_Float16*)(lds + 49152);    // 48KB
  _Float16* wHH1 = (_Float16*)(lds + 98304);    // 48KB
  _Float16* wIH0 = (_Float16*)(lds + 147456);   // 15KB

  const int tid = threadIdx.x;
  const int w = tid >> 6, l = tid & 63, l15 = l & 15, lgp = l >> 4;
  const int p = w >> 1, lay = w & 1;

  int* bcast = (int*)lds;
  if (tid == 0) {
    unsigned xcc;
    asm volatile("s_getreg_b32 %0, hwreg(HW_REG_XCC_ID)" : "=s"(xcc));
    int c = (int)(xcc & 7u);
    int qq = __hip_atomic_fetch_add(&g_claim[c], 1, __ATOMIC_RELAXED, __HIP_MEMORY_SCOPE_AGENT);
    bcast[0] = c; bcast[1] = qq & 31;
  }
  __syncthreads();
  const int cl = bcast[0], q = bcast[1];
  const int j0 = q * 16;
  __syncthreads();

  for (int e = tid; e < 3*16*NH; e += 256) {
    int k = e & 511, ru = e >> 9;
    int g = ru >> 4, u = ru & 15;
    int src = (g*NH + j0 + u)*NH + k;
    int dst = ((g*16 + (k>>5))*64 + ((((k>>3)&3)<<4) | u))*8 + (k&7);
    wHH0[dst] = (_Float16)Whh0[src];
    wIH1[dst] = (_Float16)Wih1[src];
    wHH1[dst] = (_Float16)Whh1[src];
  }
  for (int e = tid; e < 3*16*160; e += 256) {
    int k = e % 160, ru = e / 160;
    int g = ru >> 4, u = ru & 15;
    float v = (k < 130) ? Wih0[(g*NH + j0 + u)*130 + k] : 0.f;
    int dst = ((g*5 + (k>>5))*64 + ((((k>>3)&3)<<4) | u))*8 + (k&7);
    wIH0[dst] = (_Float16)v;
  }

  const int ucol = j0 + l15;
  const float cbr = lay ? bih1[ucol]+bhh1[ucol]       : bih0[ucol]+bhh0[ucol];
  const float cbz = lay ? bih1[NH+ucol]+bhh1[NH+ucol] : bih0[NH+ucol]+bhh0[NH+ucol];
  const float bin = lay ? bih1[2*NH+ucol]             : bih0[2*NH+ucol];
  const float bhn = lay ? bhh1[2*NH+ucol]             : bhh0[2*NH+ucol];

  const int arow0 = (p*16 + l15)*NH + lgp*8;          // f16 units within a slot
  const int sOff  = ((cl*BCL + p*16 + l15)*BPC + lgp*8)*2;   // floats, in-plane
  const _Float16* xptr = g_xm + ((long)(cl*BCL + p*16 + l15)*NT)*XMS + lgp*8;

  const i32x4 srdH1 = make_srd(g_h1 + (size_t)cl*4*BCL*NH);
  const i32x4 srdH2 = make_srd(g_h2 + (size_t)cl*4*BCL*NH);
  const i32x4 srdST = make_srd(g_stats);

  float hloc[4] = {0,0,0,0};
  float A1[4]={0,0,0,0}, A0[4]={0,0,0,0}, lastc[4]={0,0,0,0};
  f16x8 af1[16], xmf[5];
  f32x4 sts0, sts1, sts2, sts3;
  const f32x4 z4v = {0.f,0.f,0.f,0.f};

  auto lnFinish = [&](bool last) {   // uses hloc BEFORE the gate-math update
    float s  = (sts0[0]+sts1[0]) + (sts2[0]+sts3[0]) + (sts0[2]+sts1[2]) + (sts2[2]+sts3[2]);
    float ss = (sts0[1]+sts1[1]) + (sts2[1]+sts3[1]) + (sts0[3]+sts1[3]) + (sts2[3]+sts3[3]);
    s += __shfl_xor(s,16); ss += __shfl_xor(ss,16);
    s += __shfl_xor(s,32); ss += __shfl_xor(ss,32);
    #pragma unroll
    for (int r = 0; r < 4; r++) {
      float S = __shfl(s, lgp*4+r), SS = __shfl(ss, lgp*4+r);
      float mu = S*(1.f/NH), var = SS*(1.f/NH) - mu*mu;
      float inv = rsqrtf(var + 1e-5f);
      A1[r] += hloc[r]*inv; A0[r] += mu*inv;
      if (last) lastc[r] = (hloc[r]-mu)*inv;
    }
  };
  // Paired u32 store of this wave's h tile (even lanes store 2 f16 as one
  // dword: no sub-dword RMW; memory layout identical to the f16 array).
  auto stPair = [&](_Float16* hw, int row, float v) {
    unsigned lo = (unsigned)__builtin_bit_cast(unsigned short, (_Float16)v);
    unsigned hi = (unsigned)__shfl_xor((int)lo, 1);
    if (!(l15 & 1))
      st_c((unsigned*)(hw + row*NH + j0 + l15), lo | (hi << 16));
  };

  __syncthreads();   // weight packs visible
  if (lay == 0) {    // xm(0) prefetch (plain loads; immutable data)
    #pragma unroll
    for (int c = 0; c < 5; c++) xmf[c] = *(const f16x8*)(xptr + c*32);
  }

  for (int s = 0; s <= NT+1; ++s) {
    if (lay == 0) {
      if (s < NT) {
        // fresh h1(s-1): the single tight-edge load
        const int vb = 2*(((s+3)&3)*BCL*NH + arow0);
        f16x8 ah[16];
        #pragma unroll
        for (int c = 0; c < 16; c++) ah[c] = bldh(srdH1, vb + c*64);
        f32x4 aR=z4v, aZ=z4v, aNi=z4v, aNh=z4v;
        #pragma unroll
        for (int c = 0; c < 5; c++) {
          aR  = MF(xmf[c], BI0(0,c), aR);
          aZ  = MF(xmf[c], BI0(1,c), aZ);
          aNi = MF(xmf[c], BI0(2,c), aNi);
        }
        #pragma unroll
        for (int c = 0; c < 16; c++) {
          aR  = MF(ah[c], BF(wHH0,0,c), aR);
          aZ  = MF(ah[c], BF(wHH0,1,c), aZ);
          aNh = MF(ah[c], BF(wHH0,2,c), aNh);
        }
        #pragma unroll
        for (int r = 0; r < 4; r++) {
          float rg = sigm(aR[r] + cbr);
          float zg = sigm(aZ[r] + cbz);
          float ng = tanh_(aNi[r] + bin + rg*(aNh[r] + bhn));
          hloc[r] = (1.f-zg)*ng + zg*hloc[r];
        }
        _Float16* hw = g_h1 + (size_t)(cl*4 + (s&3))*BCL*NH;
        #pragma unroll
        for (int r = 0; r < 4; r++) stPair(hw, p*16 + lgp*4 + r, hloc[r]);
      }
    } else {   // lay1: computes h2(s-2)
      if (s >= 2) {
        // h2(s-3) + stats(s-3): published 1 barrier ago; h1(s-2) prefetched
        const int vb2 = 2*(((s+1)&3)*BCL*NH + arow0);
        f16x8 ag2[16];
        #pragma unroll
        for (int c = 0; c < 16; c++) ag2[c] = bldh(srdH2, vb2 + c*64);
        const int vbs = 4*(((s+1)&1)*STPL + sOff);
        sts0 = __builtin_bit_cast(f32x4, bld(srdST, vbs));
        sts1 = __builtin_bit_cast(f32x4, bld(srdST, vbs + 16));
        sts2 = __builtin_bit_cast(f32x4, bld(srdST, vbs + 32));
        sts3 = __builtin_bit_cast(f32x4, bld(srdST, vbs + 48));
        f32x4 aR=z4v, aZ=z4v, aNi=z4v, aNh=z4v;
        #pragma unroll
        for (int c = 0; c < 16; c++) {   // ih1 first: af1 already resident
          aR  = MF(af1[c], BF(wIH1,0,c), aR);
          aZ  = MF(af1[c], BF(wIH1,1,c), aZ);
          aNi = MF(af1[c], BF(wIH1,2,c), aNi);
        }
        #pragma unroll
        for (int c = 0; c < 16; c++) {   // hh1: waits ag2 (hidden under ih1)
          aR  = MF(ag2[c], BF(wHH1,0,c), aR);
          aZ  = MF(ag2[c], BF(wHH1,1,c), aZ);
          aNh = MF(ag2[c], BF(wHH1,2,c), aNh);
        }
        if (s >= 3) lnFinish(false);   // t=s-3, hloc still h2(s-3)
        _Float16* hw = g_h2 + (size_t)(cl*4 + ((s+2)&3))*BCL*NH;
        float* swb = g_stats[s&1];
        #pragma unroll
        for (int r = 0; r < 4; r++) {
          int row = p*16 + lgp*4 + r;
          float rg = sigm(aR[r] + cbr);
          float zg = sigm(aZ[r] + cbz);
          float ng = tanh_(aNi[r] + bin + rg*(aNh[r] + bhn));
          hloc[r] = (1.f-zg)*ng + zg*hloc[r];
          stPair(hw, row, hloc[r]);
          float v = hloc[r], v2 = hloc[r]*hloc[r];
          v += __shfl_xor(v,1); v2 += __shfl_xor(v2,1);
          v += __shfl_xor(v,2); v2 += __shfl_xor(v2,2);
          v += __shfl_xor(v,4); v2 += __shfl_xor(v2,4);
          v += __shfl_xor(v,8); v2 += __shfl_xor(v2,8);
          if (l15 == 0) {
            unsigned long long sv =
                (unsigned long long)__builtin_bit_cast(unsigned, v)
              | ((unsigned long long)__builtin_bit_cast(unsigned, v2) << 32);
            st_c64((unsigned long long*)(swb + ((cl*BCL + row)*BPC + q)*2), sv);
          }
        }
      }
    }

    __syncthreads();   // drains every wave's agent stores (vmcnt0 at barrier)
    if (tid == 0)
      __hip_atomic_fetch_add(&g_cnt[cl], 1, __ATOMIC_RELAXED, __HIP_MEMORY_SCOPE_AGENT);
    // cross-barrier prefetches (data published >= 1 barrier ago; intrinsic
    // loads are spill-safe, so surviving the poll loop is correct by
    // construction — the waitcnt pass guards every use)
    if (lay == 1 && s >= 1 && s <= NT) {   // h1(s-1) for next superstep's ih1
      const int vb1 = 2*(((s+3)&3)*BCL*NH + arow0);
      #pragma unroll
      for (int c = 0; c < 16; c++) af1[c] = bldh(srdH1, vb1 + c*64);
    }
    if (lay == 0 && s + 1 < NT) {          // xm(s+1), immutable
      xptr += XMS;
      #pragma unroll
      for (int c = 0; c < 5; c++) xmf[c] = *(const f16x8*)(xptr + c*32);
    }
    const int tgt = 32*(s+1);              // per-wave self-release
    while (ld_fl(&g_cnt[cl]) < tgt) __builtin_amdgcn_s_sleep(1);
  }

  if (lay == 1) {   // final LN for t=NT-1 (stats parity 1) + pooled write
    const int vbs = 4*(1*STPL + sOff);
    sts0 = __builtin_bit_cast(f32x4, bld(srdST, vbs));
    sts1 = __builtin_bit_cast(f32x4, bld(srdST, vbs + 16));
    sts2 = __builtin_bit_cast(f32x4, bld(srdST, vbs + 32));
    sts3 = __builtin_bit_cast(f32x4, bld(srdST, vbs + 48));
    lnFinish(true);
    float gg = lng[ucol], bb = lnb[ucol];
    #pragma unroll
    for (int r = 0; r < 4; r++) {
      float v = gg*(lastc[r] + (A1[r]-A0[r])*(1.f/NT)) + 2.f*bb;
      g_pool[(cl*BCL + p*16 + lgp*4 + r)*NH + ucol] = v;
    }
  }
}

__global__ __launch_bounds__(256) void proj_kernel(const float* __restrict__ bp,
                                                   float* __restrict__ out) {
  __shared__ float pr[NH];
  int b = blockIdx.x, o = threadIdx.x;
  pr[o] = g_pool[b*NH + o];
  pr[o+256] = g_pool[b*NH + 256 + o];
  __syncthreads();
  float acc = bp[o];
  #pragma unroll 8
  for (int u = 0; u < NH; ++u) acc = fmaf(pr[u], g_Wt[u*256 + o], acc);
  out[b*256 + o] = 0.5f*acc*(1.f + erff(acc*0.70710678118654752f));
}

extern "C" void kernel_launch(void* const* d_in, const int* in_sizes, int n_in,
                              void* d_out, int out_size, void* d_ws, size_t ws_size,
                              hipStream_t stream) {
  const float* x    = (const float*)d_in[0];
  const int*   mask = (const int*)d_in[1];
  const float* Wih0 = (const float*)d_in[2];
  const float* Whh0 = (const float*)d_in[3];
  const float* bih0 = (const float*)d_in[4];
  const float* bhh0 = (const float*)d_in[5];
  const float* Wih1 = (const float*)d_in[6];
  const float* Whh1 = (const float*)d_in[7];
  const float* bih1 = (const float*)d_in[8];
  const float* bhh1 = (const float*)d_in[9];
  const float* lng  = (const float*)d_in[10];
  const float* lnb  = (const float*)d_in[11];
  const float* Wp   = (const float*)d_in[12];
  const float* bp   = (const float*)d_in[13];
  float* out = (float*)d_out;
  (void)in_sizes; (void)n_in; (void)out_size; (void)d_ws; (void)ws_size;

  hipFuncSetAttribute(reinterpret_cast<const void*>(gru_main),
                      hipFuncAttributeMaxDynamicSharedMemorySize, 162816);

  hipLaunchKernelGGL(init_kernel, dim3(2048), dim3(256), 0, stream, Wp, x, mask);
  hipLaunchKernelGGL(gru_main, dim3(256), dim3(256), 162816, stream,
                     Wih0, Whh0, bih0, bhh0, Wih1, Whh1, bih1, bhh1, lng, lnb);
  hipLaunchKernelGGL(proj_kernel, dim3(NB), dim3(256), 0, stream, bp, out);
}